// Round 15
// baseline (26.286 us; speedup 1.0000x reference)
//
#include <hip/hip_runtime.h>

typedef _Float16 f16x8  __attribute__((ext_vector_type(8)));
typedef float    f32x16 __attribute__((ext_vector_type(16)));

static constexpr int BATCH = 4;
static constexpr int NPTS  = 8192;
static constexpr int NPROB = 2 * BATCH;       // (batch, direction) = 8
static constexpr int RR    = 8;               // ref chunks per problem
static constexpr int RBLK  = NPTS / RR;       // 1024 refs staged per block (16 KB)
static constexpr int TPB   = 256;             // 4 waves
static constexpr int WQ    = 128;             // queries per wave (4 MFMA col-groups)
static constexpr int QBLK  = (TPB / 64) * WQ; // 512 queries per block
static constexpr int NQB   = NPTS / QBLK;     // 16 query tiles
static constexpr float CSHIFT = 128.0f;       // makes every candidate positive

__device__ __forceinline__ unsigned packh2(_Float16 lo, _Float16 hi) {
    union { _Float16 h[2]; unsigned u; } v;
    v.h[0] = lo; v.h[1] = hi;
    return v.u;
}

__device__ __forceinline__ int imin(int a, int b) { return a < b ? a : b; }

// INTEGER-domain fold. fminf on MFMA results forces fcanonicalize (v_max x,x,x)
// per element in IEEE mode (MFMA intrinsic results are not provably-canonical to
// LLVM) -> 32 VALU/MFMA instead of 16. Candidates are made strictly positive
// (yy+128-2dot >= 79 > 0), so int ordering == float ordering: v_min3_i32 fusion,
// no canonicalization, bit-identical min result. NO inline asm (R6/R13 lesson:
// inline asm consuming MFMA results misses hazard wait-states -> garbage).
#define FI(x) __float_as_int(x)
#define FOLD(d, mA, mB)                                        \
    do {                                                       \
        mA = imin(imin(FI((d)[0]),  FI((d)[1])),  mA);         \
        mA = imin(imin(FI((d)[2]),  FI((d)[3])),  mA);         \
        mA = imin(imin(FI((d)[4]),  FI((d)[5])),  mA);         \
        mA = imin(imin(FI((d)[6]),  FI((d)[7])),  mA);         \
        mB = imin(imin(FI((d)[8]),  FI((d)[9])),  mB);         \
        mB = imin(imin(FI((d)[10]), FI((d)[11])), mB);         \
        mB = imin(imin(FI((d)[12]), FI((d)[13])), mB);         \
        mB = imin(imin(FI((d)[14]), FI((d)[15])), mB);         \
    } while (0)

// ---------------- pass 1: per-(qtile, refchunk, prob) partial NN min via MFMA ----------------
__global__ __launch_bounds__(TPB, 4) void cd_pass1(const float* __restrict__ gen,
                                                   const float* __restrict__ train,
                                                   float* __restrict__ pmin,
                                                   unsigned long long* __restrict__ acc,
                                                   unsigned* __restrict__ cnt) {
    __shared__ uint4 rA[RBLK];                // 16 KB packed refs (order-scrambled: min-safe)
    const int qb = blockIdx.x, rr = blockIdx.y, prob = blockIdx.z;
    if (qb == 0 && rr == 0 && prob == 0 && threadIdx.x == 0) { *acc = 0ull; *cnt = 0u; }
    const int b = prob >> 1, dir = prob & 1;
    const float* qbase = (dir == 0 ? gen : train) + (size_t)b * NPTS * 3;
    const float* rbase = (dir == 0 ? train : gen) + (size_t)b * NPTS * 3;
    const int lane = threadIdx.x & 63, wave = threadIdx.x >> 6;

    // Stage+pack: thread t loads 4 consecutive points (12 floats, float4-aligned),
    // writes TRANSPOSED rA[i*256+t] (conflict-free ds_write_b128). The packed row is
    // (-2x,-2y,-2z, yh, yl) with yh+yl ~= yy + CSHIFT (hi/lo f16 split, abs err ~3e-5).
    {
        const float4* s4 = (const float4*)(rbase + rr * (RBLK * 3)) + threadIdx.x * 3;
        const float4 v0 = s4[0], v1 = s4[1], v2 = s4[2];
        const float px[4] = {v0.x, v0.w, v1.z, v2.y};
        const float py[4] = {v0.y, v1.x, v1.w, v2.z};
        const float pz[4] = {v0.z, v1.y, v2.x, v2.w};
        #pragma unroll
        for (int i = 0; i < 4; ++i) {
            const _Float16 hx = (_Float16)px[i], hy = (_Float16)py[i], hz = (_Float16)pz[i];
            const float xr = (float)hx, yr = (float)hy, zr = (float)hz;   // exact
            const float yyC = fmaf(xr, xr, fmaf(yr, yr, zr * zr)) + CSHIFT;
            const _Float16 yh = (_Float16)yyC;
            const _Float16 yl = (_Float16)(yyC - (float)yh);              // hi/lo split
            rA[i * TPB + threadIdx.x] =
                make_uint4(packh2((_Float16)(-2.0f * xr), (_Float16)(-2.0f * yr)),
                           packh2((_Float16)(-2.0f * zr), yh),
                           packh2(yl, (_Float16)0.0f), 0u);
        }
    }

    // Four query fragments per wave: 32 queries each; B k-vec = [qx,qy,qz,1,1,0,0,0]
    const int qid0 = qb * QBLK + wave * WQ + (lane & 31);
    const int qid1 = qid0 + 32, qid2 = qid0 + 64, qid3 = qid0 + 96;
    float qq0 = 0.0f, qq1 = 0.0f, qq2 = 0.0f, qq3 = 0.0f;
    union { uint4 u; f16x8 h; } B0, B1, B2, B3;
    B0.u = make_uint4(0u, 0u, 0u, 0u);
    B1.u = make_uint4(0u, 0u, 0u, 0u);
    B2.u = make_uint4(0u, 0u, 0u, 0u);
    B3.u = make_uint4(0u, 0u, 0u, 0u);
    if (lane < 32) {
        {
            const float qx = qbase[qid0*3+0], qy = qbase[qid0*3+1], qz = qbase[qid0*3+2];
            const _Float16 hx = (_Float16)qx, hy = (_Float16)qy, hz = (_Float16)qz;
            const float xr = (float)hx, yr = (float)hy, zr = (float)hz;
            qq0  = fmaf(xr, xr, fmaf(yr, yr, zr * zr));
            B0.u = make_uint4(packh2(hx, hy),
                              packh2(hz, (_Float16)0.0f) | 0x3C000000u, 0x3C00u, 0u);
        }
        {
            const float qx = qbase[qid1*3+0], qy = qbase[qid1*3+1], qz = qbase[qid1*3+2];
            const _Float16 hx = (_Float16)qx, hy = (_Float16)qy, hz = (_Float16)qz;
            const float xr = (float)hx, yr = (float)hy, zr = (float)hz;
            qq1  = fmaf(xr, xr, fmaf(yr, yr, zr * zr));
            B1.u = make_uint4(packh2(hx, hy),
                              packh2(hz, (_Float16)0.0f) | 0x3C000000u, 0x3C00u, 0u);
        }
        {
            const float qx = qbase[qid2*3+0], qy = qbase[qid2*3+1], qz = qbase[qid2*3+2];
            const _Float16 hx = (_Float16)qx, hy = (_Float16)qy, hz = (_Float16)qz;
            const float xr = (float)hx, yr = (float)hy, zr = (float)hz;
            qq2  = fmaf(xr, xr, fmaf(yr, yr, zr * zr));
            B2.u = make_uint4(packh2(hx, hy),
                              packh2(hz, (_Float16)0.0f) | 0x3C000000u, 0x3C00u, 0u);
        }
        {
            const float qx = qbase[qid3*3+0], qy = qbase[qid3*3+1], qz = qbase[qid3*3+2];
            const _Float16 hx = (_Float16)qx, hy = (_Float16)qy, hz = (_Float16)qz;
            const float xr = (float)hx, yr = (float)hy, zr = (float)hz;
            qq3  = fmaf(xr, xr, fmaf(yr, yr, zr * zr));
            B3.u = make_uint4(packh2(hx, hy),
                              packh2(hz, (_Float16)0.0f) | 0x3C000000u, 0x3C00u, 0u);
        }
    }
    __syncthreads();

    // Software-pipelined: issue next independent MFMA, then fold the previous result.
    const int INF = 0x7F800000;
    int m0A = INF, m0B = INF, m1A = INF, m1B = INF;
    int m2A = INF, m2B = INF, m3A = INF, m3B = INF;
    const int c = lane & 31;
    const f32x16 zc = {};
    union { uint4 u; f16x8 h; } A0, A1;

    A0.u = rA[c];                                            // tile 0 A-fragment
    f32x16 dP = __builtin_amdgcn_mfma_f32_32x32x16_f16(A0.h, B0.h, zc, 0, 0, 0);

    #pragma unroll 4
    for (int t = 0; t < RBLK / 32 - 1; ++t) {
        f32x16 d1 = __builtin_amdgcn_mfma_f32_32x32x16_f16(A0.h, B1.h, zc, 0, 0, 0);
        FOLD(dP, m0A, m0B);                                  // fold B0 @ tile t
        __builtin_amdgcn_sched_barrier(0);
        f32x16 d2 = __builtin_amdgcn_mfma_f32_32x32x16_f16(A0.h, B2.h, zc, 0, 0, 0);
        FOLD(d1, m1A, m1B);
        __builtin_amdgcn_sched_barrier(0);
        f32x16 d3 = __builtin_amdgcn_mfma_f32_32x32x16_f16(A0.h, B3.h, zc, 0, 0, 0);
        FOLD(d2, m2A, m2B);
        __builtin_amdgcn_sched_barrier(0);
        A1.u = rA[(t + 1) * 32 + c];                         // next tile A-fragment
        dP = __builtin_amdgcn_mfma_f32_32x32x16_f16(A1.h, B0.h, zc, 0, 0, 0);
        FOLD(d3, m3A, m3B);
        __builtin_amdgcn_sched_barrier(0);
        A0.u = A1.u;
    }
    // epilogue: tile 31 (dP already holds B0 @ 31)
    {
        f32x16 e1 = __builtin_amdgcn_mfma_f32_32x32x16_f16(A0.h, B1.h, zc, 0, 0, 0);
        FOLD(dP, m0A, m0B);
        __builtin_amdgcn_sched_barrier(0);
        f32x16 e2 = __builtin_amdgcn_mfma_f32_32x32x16_f16(A0.h, B2.h, zc, 0, 0, 0);
        FOLD(e1, m1A, m1B);
        __builtin_amdgcn_sched_barrier(0);
        f32x16 e3 = __builtin_amdgcn_mfma_f32_32x32x16_f16(A0.h, B3.h, zc, 0, 0, 0);
        FOLD(e2, m2A, m2B);
        __builtin_amdgcn_sched_barrier(0);
        FOLD(e3, m3A, m3B);
    }

    int m0 = imin(m0A, m0B);
    int m1 = imin(m1A, m1B);
    int m2 = imin(m2A, m2B);
    int m3 = imin(m3A, m3B);
    m0 = imin(m0, __shfl_xor(m0, 32));        // fold the two 16-row halves
    m1 = imin(m1, __shfl_xor(m1, 32));
    m2 = imin(m2, __shfl_xor(m2, 32));
    m3 = imin(m3, __shfl_xor(m3, 32));
    if (lane < 32) {
        float* dst = pmin + ((size_t)prob * RR + rr) * NPTS;
        dst[qid0] = (__int_as_float(m0) - CSHIFT) + qq0;   // plain stores, no atomics
        dst[qid1] = (__int_as_float(m1) - CSHIFT) + qq1;
        dst[qid2] = (__int_as_float(m2) - CSHIFT) + qq2;
        dst[qid3] = (__int_as_float(m3) - CSHIFT) + qq3;
    }
}

// ---------------- pass 2: fold RR partial mins, clamp, deterministic global sum ----------------
__global__ __launch_bounds__(1024) void cd_pass2(const float* __restrict__ pmin,
                                                 unsigned long long* __restrict__ acc,
                                                 unsigned* __restrict__ cnt,
                                                 float* __restrict__ out) {
    const int g = blockIdx.x * 1024 + threadIdx.x;   // 64 blocks x 1024 = 65536 queries
    const int prob = g >> 13, qid = g & (NPTS - 1);
    const float* p = pmin + (size_t)prob * RR * NPTS + qid;
    float m = p[0];
    #pragma unroll
    for (int r = 1; r < RR; ++r) m = fminf(m, p[(size_t)r * NPTS]);
    float d = fmaxf(m, 0.0f);

    #pragma unroll
    for (int off = 32; off >= 1; off >>= 1) d += __shfl_xor(d, off);
    __shared__ float w[16];
    const int wave = threadIdx.x >> 6, lane = threadIdx.x & 63;
    if (lane == 0) w[wave] = d;
    __syncthreads();
    if (threadIdx.x == 0) {
        float t = 0.0f;
        #pragma unroll
        for (int i = 0; i < 16; ++i) t += w[i];
        // fixed-point (2^30) integer add: order-independent -> deterministic
        unsigned long long q = (unsigned long long)((double)t * 1073741824.0 + 0.5);
        atomicAdd(acc, q);
        __threadfence();
        unsigned old = atomicAdd(cnt, 1u);
        if (old == gridDim.x - 1) {           // last block finalizes
            unsigned long long v = atomicAdd(acc, 0ull);   // coherent read via RMW
            out[0] = (float)((double)v * (1.0 / 1073741824.0) * (0.5 / BATCH));
        }
    }
}

extern "C" void kernel_launch(void* const* d_in, const int* in_sizes, int n_in,
                              void* d_out, int out_size, void* d_ws, size_t ws_size,
                              hipStream_t stream) {
    const float* gen   = (const float*)d_in[0];   // [4,8192,3] f32
    const float* train = (const float*)d_in[1];   // [4,8192,3] f32
    char* ws = (char*)d_ws;
    float* pmin = (float*)ws;                                  // 2 MB partial mins
    unsigned long long* acc = (unsigned long long*)(ws + 0x200000);
    unsigned* cnt = (unsigned*)(ws + 0x200008);
    float* out = (float*)d_out;

    cd_pass1<<<dim3(NQB, RR, NPROB), TPB, 0, stream>>>(gen, train, pmin, acc, cnt);
    cd_pass2<<<64, 1024, 0, stream>>>(pmin, acc, cnt, out);
}

// Round 16
// 26.271 us; speedup vs baseline: 1.0006x; 1.0006x over previous
//
#include <hip/hip_runtime.h>

typedef _Float16 f16x8  __attribute__((ext_vector_type(8)));
typedef float    f32x16 __attribute__((ext_vector_type(16)));

static constexpr int BATCH = 4;
static constexpr int NPTS  = 8192;
static constexpr int NPROB = 2 * BATCH;       // (batch, direction) = 8
static constexpr int RR    = 8;               // ref chunks per problem
static constexpr int RBLK  = NPTS / RR;       // 1024 refs staged per block (16 KB)
static constexpr int TPB   = 256;             // 4 waves
static constexpr int WQ    = 128;             // queries per wave (4 MFMA col-groups)
static constexpr int QBLK  = (TPB / 64) * WQ; // 512 queries per block
static constexpr int NQB   = NPTS / QBLK;     // 16 query tiles
static constexpr float CSHIFT = 128.0f;       // makes every candidate positive

__device__ __forceinline__ unsigned packh2(_Float16 lo, _Float16 hi) {
    union { _Float16 h[2]; unsigned u; } v;
    v.h[0] = lo; v.h[1] = hi;
    return v.u;
}

__device__ __forceinline__ int imin(int a, int b) { return a < b ? a : b; }

// Integer-domain fold on positive floats (int order == float order), no
// fcanonicalize. The "+v" pin (see loop) keeps d in arch VGPRs so
// v_min3_i32 can encode its operands directly (AGPR-resident MFMA results
// would force v_accvgpr_read shuttles: ~16 extra VALU/MFMA, R9 VGPR=40).
#define FI(x) __float_as_int(x)
#define FOLD(d, mA, mB)                                        \
    do {                                                       \
        mA = imin(imin(FI((d)[0]),  FI((d)[1])),  mA);         \
        mA = imin(imin(FI((d)[2]),  FI((d)[3])),  mA);         \
        mA = imin(imin(FI((d)[4]),  FI((d)[5])),  mA);         \
        mA = imin(imin(FI((d)[6]),  FI((d)[7])),  mA);         \
        mB = imin(imin(FI((d)[8]),  FI((d)[9])),  mB);         \
        mB = imin(imin(FI((d)[10]), FI((d)[11])), mB);         \
        mB = imin(imin(FI((d)[12]), FI((d)[13])), mB);         \
        mB = imin(imin(FI((d)[14]), FI((d)[15])), mB);         \
    } while (0)

// empty-asm VGPR pin: no instructions, just a register-class constraint
#define PIN(d) asm volatile("" : "+v"(d))

// ---------------- pass 1: per-(qtile, refchunk, prob) partial NN min via MFMA ----------------
__global__ __launch_bounds__(TPB, 4) void cd_pass1(const float* __restrict__ gen,
                                                   const float* __restrict__ train,
                                                   float* __restrict__ pmin,
                                                   unsigned long long* __restrict__ acc,
                                                   unsigned* __restrict__ cnt) {
    __shared__ uint4 rA[RBLK];                // 16 KB packed refs (order-scrambled: min-safe)
    const int qb = blockIdx.x, rr = blockIdx.y, prob = blockIdx.z;
    if (qb == 0 && rr == 0 && prob == 0 && threadIdx.x == 0) { *acc = 0ull; *cnt = 0u; }
    const int b = prob >> 1, dir = prob & 1;
    const float* qbase = (dir == 0 ? gen : train) + (size_t)b * NPTS * 3;
    const float* rbase = (dir == 0 ? train : gen) + (size_t)b * NPTS * 3;
    const int lane = threadIdx.x & 63, wave = threadIdx.x >> 6;

    // Stage+pack: thread t loads 4 consecutive points (12 floats, float4-aligned),
    // writes TRANSPOSED rA[i*256+t] (conflict-free ds_write_b128). The packed row is
    // (-2x,-2y,-2z, yh, yl) with yh+yl ~= yy + CSHIFT (hi/lo f16 split).
    {
        const float4* s4 = (const float4*)(rbase + rr * (RBLK * 3)) + threadIdx.x * 3;
        const float4 v0 = s4[0], v1 = s4[1], v2 = s4[2];
        const float px[4] = {v0.x, v0.w, v1.z, v2.y};
        const float py[4] = {v0.y, v1.x, v1.w, v2.z};
        const float pz[4] = {v0.z, v1.y, v2.x, v2.w};
        #pragma unroll
        for (int i = 0; i < 4; ++i) {
            const _Float16 hx = (_Float16)px[i], hy = (_Float16)py[i], hz = (_Float16)pz[i];
            const float xr = (float)hx, yr = (float)hy, zr = (float)hz;   // exact
            const float yyC = fmaf(xr, xr, fmaf(yr, yr, zr * zr)) + CSHIFT;
            const _Float16 yh = (_Float16)yyC;
            const _Float16 yl = (_Float16)(yyC - (float)yh);              // hi/lo split
            rA[i * TPB + threadIdx.x] =
                make_uint4(packh2((_Float16)(-2.0f * xr), (_Float16)(-2.0f * yr)),
                           packh2((_Float16)(-2.0f * zr), yh),
                           packh2(yl, (_Float16)0.0f), 0u);
        }
    }

    // Four query fragments per wave: 32 queries each; B k-vec = [qx,qy,qz,1,1,0,0,0]
    const int qid0 = qb * QBLK + wave * WQ + (lane & 31);
    const int qid1 = qid0 + 32, qid2 = qid0 + 64, qid3 = qid0 + 96;
    float qq0 = 0.0f, qq1 = 0.0f, qq2 = 0.0f, qq3 = 0.0f;
    union { uint4 u; f16x8 h; } B0, B1, B2, B3;
    B0.u = make_uint4(0u, 0u, 0u, 0u);
    B1.u = make_uint4(0u, 0u, 0u, 0u);
    B2.u = make_uint4(0u, 0u, 0u, 0u);
    B3.u = make_uint4(0u, 0u, 0u, 0u);
    if (lane < 32) {
        {
            const float qx = qbase[qid0*3+0], qy = qbase[qid0*3+1], qz = qbase[qid0*3+2];
            const _Float16 hx = (_Float16)qx, hy = (_Float16)qy, hz = (_Float16)qz;
            const float xr = (float)hx, yr = (float)hy, zr = (float)hz;
            qq0  = fmaf(xr, xr, fmaf(yr, yr, zr * zr));
            B0.u = make_uint4(packh2(hx, hy),
                              packh2(hz, (_Float16)0.0f) | 0x3C000000u, 0x3C00u, 0u);
        }
        {
            const float qx = qbase[qid1*3+0], qy = qbase[qid1*3+1], qz = qbase[qid1*3+2];
            const _Float16 hx = (_Float16)qx, hy = (_Float16)qy, hz = (_Float16)qz;
            const float xr = (float)hx, yr = (float)hy, zr = (float)hz;
            qq1  = fmaf(xr, xr, fmaf(yr, yr, zr * zr));
            B1.u = make_uint4(packh2(hx, hy),
                              packh2(hz, (_Float16)0.0f) | 0x3C000000u, 0x3C00u, 0u);
        }
        {
            const float qx = qbase[qid2*3+0], qy = qbase[qid2*3+1], qz = qbase[qid2*3+2];
            const _Float16 hx = (_Float16)qx, hy = (_Float16)qy, hz = (_Float16)qz;
            const float xr = (float)hx, yr = (float)hy, zr = (float)hz;
            qq2  = fmaf(xr, xr, fmaf(yr, yr, zr * zr));
            B2.u = make_uint4(packh2(hx, hy),
                              packh2(hz, (_Float16)0.0f) | 0x3C000000u, 0x3C00u, 0u);
        }
        {
            const float qx = qbase[qid3*3+0], qy = qbase[qid3*3+1], qz = qbase[qid3*3+2];
            const _Float16 hx = (_Float16)qx, hy = (_Float16)qy, hz = (_Float16)qz;
            const float xr = (float)hx, yr = (float)hy, zr = (float)hz;
            qq3  = fmaf(xr, xr, fmaf(yr, yr, zr * zr));
            B3.u = make_uint4(packh2(hx, hy),
                              packh2(hz, (_Float16)0.0f) | 0x3C000000u, 0x3C00u, 0u);
        }
    }
    __syncthreads();

    // Software-pipelined: issue next independent MFMA, then fold the previous
    // (VGPR-pinned) result.
    const int INF = 0x7F800000;
    int m0A = INF, m0B = INF, m1A = INF, m1B = INF;
    int m2A = INF, m2B = INF, m3A = INF, m3B = INF;
    const int c = lane & 31;
    const f32x16 zc = {};
    union { uint4 u; f16x8 h; } A0, A1;

    A0.u = rA[c];                                            // tile 0 A-fragment
    f32x16 dP = __builtin_amdgcn_mfma_f32_32x32x16_f16(A0.h, B0.h, zc, 0, 0, 0);
    PIN(dP);

    #pragma unroll 4
    for (int t = 0; t < RBLK / 32 - 1; ++t) {
        f32x16 d1 = __builtin_amdgcn_mfma_f32_32x32x16_f16(A0.h, B1.h, zc, 0, 0, 0);
        PIN(d1);
        FOLD(dP, m0A, m0B);                                  // fold B0 @ tile t
        __builtin_amdgcn_sched_barrier(0);
        f32x16 d2 = __builtin_amdgcn_mfma_f32_32x32x16_f16(A0.h, B2.h, zc, 0, 0, 0);
        PIN(d2);
        FOLD(d1, m1A, m1B);
        __builtin_amdgcn_sched_barrier(0);
        f32x16 d3 = __builtin_amdgcn_mfma_f32_32x32x16_f16(A0.h, B3.h, zc, 0, 0, 0);
        PIN(d3);
        FOLD(d2, m2A, m2B);
        __builtin_amdgcn_sched_barrier(0);
        A1.u = rA[(t + 1) * 32 + c];                         // next tile A-fragment
        dP = __builtin_amdgcn_mfma_f32_32x32x16_f16(A1.h, B0.h, zc, 0, 0, 0);
        PIN(dP);
        FOLD(d3, m3A, m3B);
        __builtin_amdgcn_sched_barrier(0);
        A0.u = A1.u;
    }
    // epilogue: tile 31 (dP already holds B0 @ 31)
    {
        f32x16 e1 = __builtin_amdgcn_mfma_f32_32x32x16_f16(A0.h, B1.h, zc, 0, 0, 0);
        PIN(e1);
        FOLD(dP, m0A, m0B);
        __builtin_amdgcn_sched_barrier(0);
        f32x16 e2 = __builtin_amdgcn_mfma_f32_32x32x16_f16(A0.h, B2.h, zc, 0, 0, 0);
        PIN(e2);
        FOLD(e1, m1A, m1B);
        __builtin_amdgcn_sched_barrier(0);
        f32x16 e3 = __builtin_amdgcn_mfma_f32_32x32x16_f16(A0.h, B3.h, zc, 0, 0, 0);
        PIN(e3);
        FOLD(e2, m2A, m2B);
        __builtin_amdgcn_sched_barrier(0);
        FOLD(e3, m3A, m3B);
    }

    int m0 = imin(m0A, m0B);
    int m1 = imin(m1A, m1B);
    int m2 = imin(m2A, m2B);
    int m3 = imin(m3A, m3B);
    m0 = imin(m0, __shfl_xor(m0, 32));        // fold the two 16-row halves
    m1 = imin(m1, __shfl_xor(m1, 32));
    m2 = imin(m2, __shfl_xor(m2, 32));
    m3 = imin(m3, __shfl_xor(m3, 32));
    if (lane < 32) {
        float* dst = pmin + ((size_t)prob * RR + rr) * NPTS;
        dst[qid0] = (__int_as_float(m0) - CSHIFT) + qq0;   // plain stores, no atomics
        dst[qid1] = (__int_as_float(m1) - CSHIFT) + qq1;
        dst[qid2] = (__int_as_float(m2) - CSHIFT) + qq2;
        dst[qid3] = (__int_as_float(m3) - CSHIFT) + qq3;
    }
}

// ---------------- pass 2: fold RR partial mins, clamp, deterministic global sum ----------------
__global__ __launch_bounds__(1024) void cd_pass2(const float* __restrict__ pmin,
                                                 unsigned long long* __restrict__ acc,
                                                 unsigned* __restrict__ cnt,
                                                 float* __restrict__ out) {
    const int g = blockIdx.x * 1024 + threadIdx.x;   // 64 blocks x 1024 = 65536 queries
    const int prob = g >> 13, qid = g & (NPTS - 1);
    const float* p = pmin + (size_t)prob * RR * NPTS + qid;
    float m = p[0];
    #pragma unroll
    for (int r = 1; r < RR; ++r) m = fminf(m, p[(size_t)r * NPTS]);
    float d = fmaxf(m, 0.0f);

    #pragma unroll
    for (int off = 32; off >= 1; off >>= 1) d += __shfl_xor(d, off);
    __shared__ float w[16];
    const int wave = threadIdx.x >> 6, lane = threadIdx.x & 63;
    if (lane == 0) w[wave] = d;
    __syncthreads();
    if (threadIdx.x == 0) {
        float t = 0.0f;
        #pragma unroll
        for (int i = 0; i < 16; ++i) t += w[i];
        // fixed-point (2^30) integer add: order-independent -> deterministic
        unsigned long long q = (unsigned long long)((double)t * 1073741824.0 + 0.5);
        atomicAdd(acc, q);
        __threadfence();
        unsigned old = atomicAdd(cnt, 1u);
        if (old == gridDim.x - 1) {           // last block finalizes
            unsigned long long v = atomicAdd(acc, 0ull);   // coherent read via RMW
            out[0] = (float)((double)v * (1.0 / 1073741824.0) * (0.5 / BATCH));
        }
    }
}

extern "C" void kernel_launch(void* const* d_in, const int* in_sizes, int n_in,
                              void* d_out, int out_size, void* d_ws, size_t ws_size,
                              hipStream_t stream) {
    const float* gen   = (const float*)d_in[0];   // [4,8192,3] f32
    const float* train = (const float*)d_in[1];   // [4,8192,3] f32
    char* ws = (char*)d_ws;
    float* pmin = (float*)ws;                                  // 2 MB partial mins
    unsigned long long* acc = (unsigned long long*)(ws + 0x200000);
    unsigned* cnt = (unsigned*)(ws + 0x200008);
    float* out = (float*)d_out;

    cd_pass1<<<dim3(NQB, RR, NPROB), TPB, 0, stream>>>(gen, train, pmin, acc, cnt);
    cd_pass2<<<64, 1024, 0, stream>>>(pmin, acc, cnt, out);
}

// Round 17
// 24.055 us; speedup vs baseline: 1.0927x; 1.0921x over previous
//
#include <hip/hip_runtime.h>

typedef _Float16 f16x8  __attribute__((ext_vector_type(8)));
typedef float    f32x16 __attribute__((ext_vector_type(16)));

static constexpr int BATCH = 4;
static constexpr int NPTS  = 8192;
static constexpr int NPROB = 2 * BATCH;       // (batch, direction) = 8
static constexpr int RR    = 8;               // ref chunks per problem
static constexpr int RBLK  = NPTS / RR;       // 1024 refs staged per block (16 KB)
static constexpr int TPB   = 256;             // 4 waves
static constexpr int WQ    = 128;             // queries per wave (4 MFMA col-groups)
static constexpr int QBLK  = (TPB / 64) * WQ; // 512 queries per block
static constexpr int NQB   = NPTS / QBLK;     // 16 query tiles

__device__ __forceinline__ unsigned packh2(_Float16 lo, _Float16 hi) {
    union { _Float16 h[2]; unsigned u; } v;
    v.h[0] = lo; v.h[1] = hi;
    return v.u;
}

// min(a,b) as v_med3_f32(a, b, -inf): median of {a, b, -inf} = min(a,b) for finite
// a,b (all our values are). Direct intrinsic -> no fcanonicalize insertion, unlike
// fminf (llvm.minnum), whose MFMA-result operands get a v_max x,x,x canon each in
// IEEE mode (~32-40 VALU/MFMA measured via R4 PMC). 16 v_med3 per MFMA result.
__device__ __forceinline__ float fmin2(float a, float b) {
    return __builtin_amdgcn_fmed3f(a, b, __int_as_float(0xFF800000));
}

// fold one MFMA result tile into a frag's two running-min chains: 16 x v_med3_f32
#define FOLD(d, mA, mB)                                   \
    do {                                                  \
        mA = fmin2(fmin2((d)[0],  (d)[1]),  mA);          \
        mA = fmin2(fmin2((d)[2],  (d)[3]),  mA);          \
        mA = fmin2(fmin2((d)[4],  (d)[5]),  mA);          \
        mA = fmin2(fmin2((d)[6],  (d)[7]),  mA);          \
        mB = fmin2(fmin2((d)[8],  (d)[9]),  mB);          \
        mB = fmin2(fmin2((d)[10], (d)[11]), mB);          \
        mB = fmin2(fmin2((d)[12], (d)[13]), mB);          \
        mB = fmin2(fmin2((d)[14], (d)[15]), mB);          \
    } while (0)

// ---------------- pass 1: per-(qtile, refchunk, prob) partial NN min via MFMA ----------------
__global__ __launch_bounds__(TPB, 4) void cd_pass1(const float* __restrict__ gen,
                                                   const float* __restrict__ train,
                                                   float* __restrict__ pmin,
                                                   unsigned long long* __restrict__ acc,
                                                   unsigned* __restrict__ cnt) {
    __shared__ uint4 rA[RBLK];                // 16 KB packed refs (order-scrambled: min-safe)
    const int qb = blockIdx.x, rr = blockIdx.y, prob = blockIdx.z;
    if (qb == 0 && rr == 0 && prob == 0 && threadIdx.x == 0) { *acc = 0ull; *cnt = 0u; }
    const int b = prob >> 1, dir = prob & 1;
    const float* qbase = (dir == 0 ? gen : train) + (size_t)b * NPTS * 3;
    const float* rbase = (dir == 0 ? train : gen) + (size_t)b * NPTS * 3;
    const int lane = threadIdx.x & 63, wave = threadIdx.x >> 6;

    // Stage+pack: thread t loads 4 consecutive points (12 floats, float4-aligned),
    // writes TRANSPOSED rA[i*256+t] -> consecutive lanes hit consecutive 16B slots
    // (conflict-free ds_write_b128). Point order in LDS is permuted - fine for min.
    {
        const float4* s4 = (const float4*)(rbase + rr * (RBLK * 3)) + threadIdx.x * 3;
        const float4 v0 = s4[0], v1 = s4[1], v2 = s4[2];
        const float px[4] = {v0.x, v0.w, v1.z, v2.y};
        const float py[4] = {v0.y, v1.x, v1.w, v2.z};
        const float pz[4] = {v0.z, v1.y, v2.x, v2.w};
        #pragma unroll
        for (int i = 0; i < 4; ++i) {
            const _Float16 hx = (_Float16)px[i], hy = (_Float16)py[i], hz = (_Float16)pz[i];
            const float xr = (float)hx, yr = (float)hy, zr = (float)hz;   // exact
            const float yy = fmaf(xr, xr, fmaf(yr, yr, zr * zr));
            const _Float16 yh = (_Float16)yy;
            const _Float16 yl = (_Float16)(yy - (float)yh);               // hi/lo split
            rA[i * TPB + threadIdx.x] =
                make_uint4(packh2((_Float16)(-2.0f * xr), (_Float16)(-2.0f * yr)),
                           packh2((_Float16)(-2.0f * zr), yh),
                           packh2(yl, (_Float16)0.0f), 0u);
        }
    }

    // Four query fragments per wave: 32 queries each; B k-vec = [qx,qy,qz,1,1,0,0,0]
    const int qid0 = qb * QBLK + wave * WQ + (lane & 31);
    const int qid1 = qid0 + 32, qid2 = qid0 + 64, qid3 = qid0 + 96;
    float qq0 = 0.0f, qq1 = 0.0f, qq2 = 0.0f, qq3 = 0.0f;
    union { uint4 u; f16x8 h; } B0, B1, B2, B3;
    B0.u = make_uint4(0u, 0u, 0u, 0u);
    B1.u = make_uint4(0u, 0u, 0u, 0u);
    B2.u = make_uint4(0u, 0u, 0u, 0u);
    B3.u = make_uint4(0u, 0u, 0u, 0u);
    if (lane < 32) {
        {
            const float qx = qbase[qid0*3+0], qy = qbase[qid0*3+1], qz = qbase[qid0*3+2];
            const _Float16 hx = (_Float16)qx, hy = (_Float16)qy, hz = (_Float16)qz;
            const float xr = (float)hx, yr = (float)hy, zr = (float)hz;
            qq0  = fmaf(xr, xr, fmaf(yr, yr, zr * zr));
            B0.u = make_uint4(packh2(hx, hy),
                              packh2(hz, (_Float16)0.0f) | 0x3C000000u, 0x3C00u, 0u);
        }
        {
            const float qx = qbase[qid1*3+0], qy = qbase[qid1*3+1], qz = qbase[qid1*3+2];
            const _Float16 hx = (_Float16)qx, hy = (_Float16)qy, hz = (_Float16)qz;
            const float xr = (float)hx, yr = (float)hy, zr = (float)hz;
            qq1  = fmaf(xr, xr, fmaf(yr, yr, zr * zr));
            B1.u = make_uint4(packh2(hx, hy),
                              packh2(hz, (_Float16)0.0f) | 0x3C000000u, 0x3C00u, 0u);
        }
        {
            const float qx = qbase[qid2*3+0], qy = qbase[qid2*3+1], qz = qbase[qid2*3+2];
            const _Float16 hx = (_Float16)qx, hy = (_Float16)qy, hz = (_Float16)qz;
            const float xr = (float)hx, yr = (float)hy, zr = (float)hz;
            qq2  = fmaf(xr, xr, fmaf(yr, yr, zr * zr));
            B2.u = make_uint4(packh2(hx, hy),
                              packh2(hz, (_Float16)0.0f) | 0x3C000000u, 0x3C00u, 0u);
        }
        {
            const float qx = qbase[qid3*3+0], qy = qbase[qid3*3+1], qz = qbase[qid3*3+2];
            const _Float16 hx = (_Float16)qx, hy = (_Float16)qy, hz = (_Float16)qz;
            const float xr = (float)hx, yr = (float)hy, zr = (float)hz;
            qq3  = fmaf(xr, xr, fmaf(yr, yr, zr * zr));
            B3.u = make_uint4(packh2(hx, hy),
                              packh2(hz, (_Float16)0.0f) | 0x3C000000u, 0x3C00u, 0u);
        }
    }
    __syncthreads();

    // Software-pipelined: issue next independent MFMA, then fold the previous result.
    float m0A = 3.4e38f, m0B = 3.4e38f, m1A = 3.4e38f, m1B = 3.4e38f;
    float m2A = 3.4e38f, m2B = 3.4e38f, m3A = 3.4e38f, m3B = 3.4e38f;
    const int c = lane & 31;
    const f32x16 zc = {};
    union { uint4 u; f16x8 h; } A0, A1;

    A0.u = rA[c];                                            // tile 0 A-fragment
    f32x16 dP = __builtin_amdgcn_mfma_f32_32x32x16_f16(A0.h, B0.h, zc, 0, 0, 0);

    #pragma unroll 4
    for (int t = 0; t < RBLK / 32 - 1; ++t) {
        f32x16 d1 = __builtin_amdgcn_mfma_f32_32x32x16_f16(A0.h, B1.h, zc, 0, 0, 0);
        FOLD(dP, m0A, m0B);                                  // fold B0 @ tile t
        __builtin_amdgcn_sched_barrier(0);
        f32x16 d2 = __builtin_amdgcn_mfma_f32_32x32x16_f16(A0.h, B2.h, zc, 0, 0, 0);
        FOLD(d1, m1A, m1B);
        __builtin_amdgcn_sched_barrier(0);
        f32x16 d3 = __builtin_amdgcn_mfma_f32_32x32x16_f16(A0.h, B3.h, zc, 0, 0, 0);
        FOLD(d2, m2A, m2B);
        __builtin_amdgcn_sched_barrier(0);
        A1.u = rA[(t + 1) * 32 + c];                         // next tile A-fragment
        dP = __builtin_amdgcn_mfma_f32_32x32x16_f16(A1.h, B0.h, zc, 0, 0, 0);
        FOLD(d3, m3A, m3B);
        __builtin_amdgcn_sched_barrier(0);
        A0.u = A1.u;
    }
    // epilogue: tile 31 (dP already holds B0 @ 31)
    {
        f32x16 e1 = __builtin_amdgcn_mfma_f32_32x32x16_f16(A0.h, B1.h, zc, 0, 0, 0);
        FOLD(dP, m0A, m0B);
        __builtin_amdgcn_sched_barrier(0);
        f32x16 e2 = __builtin_amdgcn_mfma_f32_32x32x16_f16(A0.h, B2.h, zc, 0, 0, 0);
        FOLD(e1, m1A, m1B);
        __builtin_amdgcn_sched_barrier(0);
        f32x16 e3 = __builtin_amdgcn_mfma_f32_32x32x16_f16(A0.h, B3.h, zc, 0, 0, 0);
        FOLD(e2, m2A, m2B);
        __builtin_amdgcn_sched_barrier(0);
        FOLD(e3, m3A, m3B);
    }

    float m0 = fmin2(m0A, m0B);
    float m1 = fmin2(m1A, m1B);
    float m2 = fmin2(m2A, m2B);
    float m3 = fmin2(m3A, m3B);
    m0 = fmin2(m0, __shfl_xor(m0, 32));       // fold the two 16-row halves
    m1 = fmin2(m1, __shfl_xor(m1, 32));
    m2 = fmin2(m2, __shfl_xor(m2, 32));
    m3 = fmin2(m3, __shfl_xor(m3, 32));
    if (lane < 32) {
        float* dst = pmin + ((size_t)prob * RR + rr) * NPTS;
        dst[qid0] = m0 + qq0;                 // plain stores, no atomics
        dst[qid1] = m1 + qq1;
        dst[qid2] = m2 + qq2;
        dst[qid3] = m3 + qq3;
    }
}

// ---------------- pass 2: fold RR partial mins, clamp, deterministic global sum ----------------
__global__ __launch_bounds__(1024) void cd_pass2(const float* __restrict__ pmin,
                                                 unsigned long long* __restrict__ acc,
                                                 unsigned* __restrict__ cnt,
                                                 float* __restrict__ out) {
    const int g = blockIdx.x * 1024 + threadIdx.x;   // 64 blocks x 1024 = 65536 queries
    const int prob = g >> 13, qid = g & (NPTS - 1);
    const float* p = pmin + (size_t)prob * RR * NPTS + qid;
    float m = p[0];
    #pragma unroll
    for (int r = 1; r < RR; ++r) m = fminf(m, p[(size_t)r * NPTS]);
    float d = fmaxf(m, 0.0f);

    #pragma unroll
    for (int off = 32; off >= 1; off >>= 1) d += __shfl_xor(d, off);
    __shared__ float w[16];
    const int wave = threadIdx.x >> 6, lane = threadIdx.x & 63;
    if (lane == 0) w[wave] = d;
    __syncthreads();
    if (threadIdx.x == 0) {
        float t = 0.0f;
        #pragma unroll
        for (int i = 0; i < 16; ++i) t += w[i];
        // fixed-point (2^30) integer add: order-independent -> deterministic
        unsigned long long q = (unsigned long long)((double)t * 1073741824.0 + 0.5);
        atomicAdd(acc, q);
        __threadfence();
        unsigned old = atomicAdd(cnt, 1u);
        if (old == gridDim.x - 1) {           // last block finalizes
            unsigned long long v = atomicAdd(acc, 0ull);   // coherent read via RMW
            out[0] = (float)((double)v * (1.0 / 1073741824.0) * (0.5 / BATCH));
        }
    }
}

extern "C" void kernel_launch(void* const* d_in, const int* in_sizes, int n_in,
                              void* d_out, int out_size, void* d_ws, size_t ws_size,
                              hipStream_t stream) {
    const float* gen   = (const float*)d_in[0];   // [4,8192,3] f32
    const float* train = (const float*)d_in[1];   // [4,8192,3] f32
    char* ws = (char*)d_ws;
    float* pmin = (float*)ws;                                  // 2 MB partial mins
    unsigned long long* acc = (unsigned long long*)(ws + 0x200000);
    unsigned* cnt = (unsigned*)(ws + 0x200008);
    float* out = (float*)d_out;

    cd_pass1<<<dim3(NQB, RR, NPROB), TPB, 0, stream>>>(gen, train, pmin, acc, cnt);
    cd_pass2<<<64, 1024, 0, stream>>>(pmin, acc, cnt, out);
}